// Round 8
// baseline (195.025 us; speedup 1.0000x reference)
//
#include <hip/hip_runtime.h>

#define K_DIM 4096
#define N_DIM 4096
#define NT (K_DIM / 64)  // 64 K-tiles, 64 bytes deep each

typedef int v4i __attribute__((ext_vector_type(4)));

__device__ __forceinline__ void gload_lds16(const void* g, void* l) {
  __builtin_amdgcn_global_load_lds(
      (const __attribute__((address_space(1))) void*)g,
      (__attribute__((address_space(3))) void*)l, 16, 0, 0);
}

__device__ __forceinline__ int pack4(int4 w) {
  return (w.x & 0xff) | ((w.y & 0xff) << 8) | ((w.z & 0xff) << 16) | (w.w << 24);
}

// fused int32 -> int8 pack for x and w (d_ws layout is contiguous: x then w)
__global__ __launch_bounds__(256) void pack_kernel(const int* __restrict__ x,
                                                   const int* __restrict__ w,
                                                   int4* __restrict__ dst, int n16x,
                                                   int n16) {
  int i = blockIdx.x * 256 + threadIdx.x;
  if (i >= n16) return;
  const int4* s = (i < n16x) ? ((const int4*)x + (size_t)i * 4)
                             : ((const int4*)w + (size_t)(i - n16x) * 4);
  int4 w0 = s[0], w1 = s[1], w2 = s[2], w3 = s[3];
  int4 r;
  r.x = pack4(w0); r.y = pack4(w1); r.z = pack4(w2); r.w = pack4(w3);
  dst[i] = r;
}

// 256x256 tile, BK=64 bytes, 8 waves (2M x 4N), mfma_i32_16x16x64_i8.
// Memory/sync skeleton is r3-verbatim (best measured, conflicts 0,
// deterministic): 4-slot circular LDS, stage(kt+3) per tile, boundary
// vmcnt(4) + ONE s_barrier per tile. Tile kt's data is drained at the end
// of tile kt-2 (one full barrier of margin); stage(kt+3) writes slot
// (kt-1)&3 whose reads drained before the previous boundary barrier.
//
// NEW vs r3: NO mid-tile barriers. The 12 ds_reads are interleaved into
// the MFMA stream (AITER pattern): {bf0..3, af0,af1} up front, then 8
// groups of {issue af[mi+2]; 4 MFMA(af[mi] x bf0..3)}, order pinned with
// sched_barrier(0). The compiler inserts exactly-counted lgkmcnt per
// group, so the LDS pipe runs in the MFMA shadow instead of serializing
// (r2/r3/r5/r7 all measured the serial sum: MfmaUtil pinned at 38-41%).
__global__ __launch_bounds__(512, 2) void gemm256(
    const char* __restrict__ Ap, const char* __restrict__ Bp,
    const int* __restrict__ bias, const float* __restrict__ pa,
    const float* __restrict__ pb, int* __restrict__ out) {
  extern __shared__ __align__(16) char lds[];  // 131072 bytes

  const int tid = threadIdx.x;
  const int wid = tid >> 6;
  const int lane = tid & 63;

  // XCD-aware bijective swizzle (nwg = 512, % 8 == 0)
  const int nwg = gridDim.x;
  const int cpx = nwg >> 3;
  const int flat = blockIdx.x;
  const int wg = (flat & 7) * cpx + (flat >> 3);
  const int br = wg >> 4;  // 0..31
  const int bn = wg & 15;  // 0..15

  const int wr = wid >> 2;   // 0..1 -> M half (128 rows)
  const int wcol = wid & 3;  // 0..3 -> N quarter (64 cols)

  // --- staging (r3-verbatim): per-lane global src, linear LDS dest ---
  const int srow = tid >> 2;                        // 0..127
  const int schunk = (tid & 3) ^ ((tid >> 3) & 3);  // inverse-swizzled chunk
  const char* aSrc = Ap + (size_t)(br * 256 + srow) * K_DIM + schunk * 16;
  const char* bSrc = Bp + (size_t)(bn * 256 + srow) * K_DIM + schunk * 16;

  auto stage = [&](int kt) {
    const char* sa = aSrc + kt * 64;
    const char* sb2 = bSrc + kt * 64;
    char* da = lds + (kt & 3) * 16384 + wid * 1024;
    char* db = lds + 65536 + (kt & 3) * 16384 + wid * 1024;
    gload_lds16(sa, da);
    gload_lds16(sa + (size_t)128 * K_DIM, da + 8192);
    gload_lds16(sb2, db);
    gload_lds16(sb2 + (size_t)128 * K_DIM, db + 8192);
  };

  // --- fragment reads (r3-verbatim, measured conflict-free) ---
  const int lrow = lane & 15;
  const int fchunk = lane >> 4;                   // 16B k-chunk 0..3
  const int rchunk = fchunk ^ ((lrow >> 1) & 3);  // swizzled slot chunk
  const int aOff = (wr * 128 + lrow) * 64 + rchunk * 16;           // + mi*1024 + slot
  const int bOff = 65536 + (wcol * 64 + lrow) * 64 + rchunk * 16;  // + ni*1024 + slot

  v4i acc[8][4];
  {
    v4i z = {0, 0, 0, 0};
#pragma unroll
    for (int mi = 0; mi < 8; ++mi)
#pragma unroll
      for (int ni = 0; ni < 4; ++ni) acc[mi][ni] = z;
  }

  // prologue: stage tiles 0,1,2; tile 0 resident before first reads
  stage(0); stage(1); stage(2);
  asm volatile("s_waitcnt vmcnt(8)" ::: "memory");
  __builtin_amdgcn_s_barrier();

  for (int kt = 0; kt < NT; ++kt) {
    const int sb = (kt & 3) * 16384;

    v4i bf[4], af[8];
    // head reads: all B + first two A
#pragma unroll
    for (int ni = 0; ni < 4; ++ni) bf[ni] = *(const v4i*)&lds[sb + bOff + ni * 1024];
    af[0] = *(const v4i*)&lds[sb + aOff + 0 * 1024];
    af[1] = *(const v4i*)&lds[sb + aOff + 1 * 1024];
    if (kt + 3 < NT) stage(kt + 3);
    __builtin_amdgcn_sched_barrier(0);

    // interleaved: issue af[mi+2] ahead, 4 MFMA per group
#pragma unroll
    for (int mi = 0; mi < 8; ++mi) {
      if (mi + 2 < 8) af[mi + 2] = *(const v4i*)&lds[sb + aOff + (mi + 2) * 1024];
      __builtin_amdgcn_sched_barrier(0);
      __builtin_amdgcn_s_setprio(1);
#pragma unroll
      for (int ni = 0; ni < 4; ++ni)
        acc[mi][ni] =
            __builtin_amdgcn_mfma_i32_16x16x64_i8(af[mi], bf[ni], acc[mi][ni], 0, 0, 0);
      __builtin_amdgcn_s_setprio(0);
      __builtin_amdgcn_sched_barrier(0);
    }

    // boundary (r3-verbatim): tile kt+2 drained for all waves + slot fence
    if (kt < NT - 3)
      asm volatile("s_waitcnt vmcnt(4)" ::: "memory");
    else
      asm volatile("s_waitcnt vmcnt(0)" ::: "memory");
    __builtin_amdgcn_s_barrier();
  }

  // epilogue: y = round(alpha*acc + beta*bias), clamp, write int32
  const float alpha = *pa;
  const float beta = *pb;
  const int rg = lane >> 4;
#pragma unroll
  for (int ni = 0; ni < 4; ++ni) {
    const int n = bn * 256 + wcol * 64 + ni * 16 + lrow;
    const float bb2 = __fmul_rn(beta, (float)bias[n]);
#pragma unroll
    for (int mi = 0; mi < 8; ++mi) {
#pragma unroll
      for (int j = 0; j < 4; ++j) {
        const int m = br * 256 + wr * 128 + mi * 16 + rg * 4 + j;
        float y = __fadd_rn(__fmul_rn(alpha, (float)acc[mi][ni][j]), bb2);
        y = rintf(y);
        y = fminf(127.f, fmaxf(-128.f, y));
        out[(size_t)m * N_DIM + n] = (int)y;
      }
    }
  }
}

extern "C" void kernel_launch(void* const* d_in, const int* in_sizes, int n_in,
                              void* d_out, int out_size, void* d_ws, size_t ws_size,
                              hipStream_t stream) {
  const int* x = (const int*)d_in[0];       // [M,K] int8 values in int32
  const int* w = (const int*)d_in[1];       // [N,K] int8 values in int32
  const int* bias = (const int*)d_in[2];    // [N] int8 values in int32
  const float* pa = (const float*)d_in[3];  // alpha
  const float* pb = (const float*)d_in[4];  // beta
  int* out = (int*)d_out;

  const int M = in_sizes[0] / K_DIM;  // 8192
  const size_t xBytes = (size_t)M * K_DIM;
  const size_t wBytes = (size_t)N_DIM * K_DIM;

  char* xp = (char*)d_ws;
  char* wp = xp + xBytes;
  const int n16x = (int)(xBytes / 16);
  const int n16 = (int)((xBytes + wBytes) / 16);
  pack_kernel<<<(n16 + 255) / 256, 256, 0, stream>>>(x, (const int*)d_in[1],
                                                     (int4*)xp, n16x, n16);

  const int nwg = (M / 256) * (N_DIM / 256);  // 512
  hipFuncSetAttribute((const void*)gemm256,
                      hipFuncAttributeMaxDynamicSharedMemorySize, 131072);
  gemm256<<<nwg, 512, 131072, stream>>>(xp, wp, bias, pa, pb, out);
}